// Round 5
// baseline (354.015 us; speedup 1.0000x reference)
//
#include <hip/hip_runtime.h>
#include <hip/hip_bf16.h>
#include <cstdint>

typedef __attribute__((ext_vector_type(16))) float f32x16;
typedef _Float16 f16x8 __attribute__((ext_vector_type(8)));

#define BN_EPS 1e-5f

// ---------------- fp32 -> fp16 cast (vectorized, 8 elems/thread) ----------------
__global__ __launch_bounds__(256)
void cast_f32_f16(const float* __restrict__ src, _Float16* __restrict__ dst, int n8) {
    int i = blockIdx.x * blockDim.x + threadIdx.x;
    if (i >= n8) return;
    const float4* s4 = (const float4*)src;
    float4 a = s4[2 * (size_t)i];
    float4 b = s4[2 * (size_t)i + 1];
    f16x8 h;
    h[0] = (_Float16)a.x; h[1] = (_Float16)a.y; h[2] = (_Float16)a.z; h[3] = (_Float16)a.w;
    h[4] = (_Float16)b.x; h[5] = (_Float16)b.y; h[6] = (_Float16)b.z; h[7] = (_Float16)b.w;
    *(f16x8*)(dst + 8 * (size_t)i) = h;
}

// async global->LDS, 16B per lane, wave-uniform LDS base
__device__ __forceinline__ void async16(const char* g, _Float16* l) {
    __builtin_amdgcn_global_load_lds(
        (const __attribute__((address_space(1))) unsigned int*)(uintptr_t)g,
        (__attribute__((address_space(3))) unsigned int*)(uintptr_t)l,
        16, 0, 0);
}

// ================= 256x256 tile, BK=32, 4-buffer, software-pipelined phases =================
// mfma_f32_32x32x16_f16. Per wave: 128x64 output = acc[4 m-frags][2 n-frags] of f32x16.
// Per K-tile(32): 2 phases (K-slices of 16). Reads for phase p+1 issue under phase p's MFMAs.
// One barrier + one counted vmcnt(4) per K-tile. Residency: end-of-kt wait retires tile kt+2;
// its first reads occur during kt+1 phase B (after that barrier). Stage of tile kt+3 writes
// buffer (kt-1)&3, whose reads all completed before the end-of-(kt-1) barrier.

struct Frags { f16x8 a[4]; f16x8 b[2]; };

__device__ __forceinline__ void loadFrags(Frags& f, const char* ab, const char* bb,
                                          int aoff, int boff) {
    #pragma unroll
    for (int mf = 0; mf < 4; ++mf) f.a[mf] = *(const f16x8*)(ab + aoff + mf * 2048);
    #pragma unroll
    for (int nf = 0; nf < 2; ++nf) f.b[nf] = *(const f16x8*)(bb + boff + nf * 2048);
}

__device__ __forceinline__ void mfmaPhase(const Frags& f, f32x16 (&acc)[4][2]) {
    __builtin_amdgcn_s_setprio(1);
    #pragma unroll
    for (int mf = 0; mf < 4; ++mf)
        #pragma unroll
        for (int nf = 0; nf < 2; ++nf)
            acc[mf][nf] = __builtin_amdgcn_mfma_f32_32x32x16_f16(f.a[mf], f.b[nf], acc[mf][nf], 0, 0, 0);
    __builtin_amdgcn_s_setprio(0);
}

__device__ __forceinline__ void stageTile(int t, _Float16* As, _Float16* Bs,
                                          const char* a0, const char* a1,
                                          const char* b0, const char* b1, int wid) {
    _Float16* dA = As + (t & 3) * 8192 + wid * 512;
    async16(a0 + (size_t)t * 64, dA);
    async16(a1 + (size_t)t * 64, dA + 4096);
    _Float16* dB = Bs + (t & 3) * 8192 + wid * 512;
    async16(b0 + (size_t)t * 64, dB);
    async16(b1 + (size_t)t * 64, dB + 4096);
}

template<int WAITN, bool STAGE, bool LAST>
__device__ __forceinline__ void ktile(
    int kt, _Float16* As, _Float16* Bs,
    const char* a0, const char* a1, const char* b0, const char* b1,
    int wid, int aoff0, int aoff1, int boff0, int boff1,
    Frags& f0, Frags& f1, f32x16 (&acc)[4][2])
{
    const char* ab = (const char*)As + ((kt & 3) << 14);
    const char* bb = (const char*)Bs + ((kt & 3) << 14);
    // ---- phase A: read (kt, ks1) under MFMA of (kt, ks0) ----
    if (STAGE) stageTile(kt + 3, As, Bs, a0, a1, b0, b1, wid);
    loadFrags(f1, ab, bb, aoff1, boff1);
    mfmaPhase(f0, acc);
    // ---- phase B: read (kt+1, ks0) under MFMA of (kt, ks1) ----
    if (!LAST) {
        const char* abn = (const char*)As + (((kt + 1) & 3) << 14);
        const char* bbn = (const char*)Bs + (((kt + 1) & 3) << 14);
        loadFrags(f0, abn, bbn, aoff0, boff0);
    }
    mfmaPhase(f1, acc);
    if (!LAST) {
        if (WAITN == 4) { asm volatile("s_waitcnt vmcnt(4)" ::: "memory"); }
        else            { asm volatile("s_waitcnt vmcnt(0)" ::: "memory"); }
        __builtin_amdgcn_s_barrier();
    }
}

__global__ __launch_bounds__(512, 2)
void gemm_gbn_kernel(const _Float16* __restrict__ A,
                     const _Float16* __restrict__ Bw,
                     const float* __restrict__ priors,
                     const float* __restrict__ gamma,
                     const float* __restrict__ beta,
                     float* __restrict__ Z,
                     int M, int N, int K)
{
    __shared__ __align__(16) _Float16 As[4 * 8192];   // 64 KB
    __shared__ __align__(16) _Float16 Bs[4 * 8192];   // 64 KB

    const int tid  = threadIdx.x;
    const int lane = tid & 63;
    const int wid  = tid >> 6;     // 0..7
    const int wr   = wid >> 2;     // 0..1  (128-row half == one virtual batch)
    const int wc   = wid & 3;      // 0..3  (64-col slice)
    const int cl   = lane & 31;    // 32x32 fragment row/col
    const int hl   = lane >> 5;    // k-half

    // XCD-aware bijective swizzle (nwg = 512, divisible by 8)
    const int bid = blockIdx.x;
    const int swz = (bid & 7) * 64 + (bid >> 3);
    const int row0 = (swz >> 2) * 256;
    const int col0 = (swz & 3) * 256;

    // staging sources (unchanged, proven): T2 pre-permuted col-slot (lane&3)^((lane>>3)&3)
    const int sperm = ((lane & 3) ^ ((lane >> 3) & 3)) * 16;
    const char* a0 = (const char*)A  + (size_t)(row0 + (tid >> 2)) * (size_t)K * 2 + sperm;
    const char* a1 = a0 + (size_t)128 * K * 2;
    const char* b0 = (const char*)Bw + (size_t)(col0 + (tid >> 2)) * (size_t)K * 2 + sperm;
    const char* b1 = b0 + (size_t)128 * K * 2;

    // LDS fragment byte offsets ([256][32] f16, 64B rows), T2-swizzled.
    // swz(x) = x ^ (((x>>7)&3)<<4); commutes with +mf*2048 / +nf*2048.
    auto swzf = [](int x) { return x ^ (((x >> 7) & 3) << 4); };
    const int arow = (wr * 128 + cl) * 64 + hl * 16;
    const int brow = (wc * 64 + cl) * 64 + hl * 16;
    const int aoff0 = swzf(arow);        // ks=0
    const int aoff1 = swzf(arow + 32);   // ks=1
    const int boff0 = swzf(brow);
    const int boff1 = swzf(brow + 32);

    f32x16 acc[4][2];
    #pragma unroll
    for (int mf = 0; mf < 4; ++mf)
        #pragma unroll
        for (int nf = 0; nf < 2; ++nf)
            acc[mf][nf] = (f32x16)0.0f;

    // prologue: stage K-tiles 0,1,2 -> buffers 0,1,2; tiles 0,1 resident after vmcnt(4)
    #pragma unroll
    for (int t = 0; t < 3; ++t) stageTile(t, As, Bs, a0, a1, b0, b1, wid);
    asm volatile("s_waitcnt vmcnt(4)" ::: "memory");
    __builtin_amdgcn_s_barrier();

    Frags f0, f1;
    loadFrags(f0, (const char*)As, (const char*)Bs, aoff0, boff0);   // (tile0, ks0)

    const int nt = K >> 5;                 // 64 K-tiles
    for (int kt = 0; kt < nt - 3; ++kt)    // stages kt+3 up to nt-1
        ktile<4, true,  false>(kt, As, Bs, a0, a1, b0, b1, wid, aoff0, aoff1, boff0, boff1, f0, f1, acc);
    ktile<0, false, false>(nt - 3, As, Bs, a0, a1, b0, b1, wid, aoff0, aoff1, boff0, boff1, f0, f1, acc);
    ktile<0, false, false>(nt - 2, As, Bs, a0, a1, b0, b1, wid, aoff0, aoff1, boff0, boff1, f0, f1, acc);
    ktile<0, false, true >(nt - 1, As, Bs, a0, a1, b0, b1, wid, aoff0, aoff1, boff0, boff1, f0, f1, acc);

    // ---- fused Ghost BatchNorm + priors epilogue ----
    // 32x32 C/D layout: col = lane&31, row = (reg&3) + 8*(reg>>2) + 4*(lane>>5)
    #pragma unroll
    for (int nf = 0; nf < 2; ++nf) {
        float s1 = 0.f, s2 = 0.f;
        #pragma unroll
        for (int mf = 0; mf < 4; ++mf)
            #pragma unroll
            for (int j = 0; j < 16; ++j) {
                float v = acc[mf][nf][j];
                s1 += v; s2 += v * v;
            }
        s1 += __shfl_xor(s1, 32); s2 += __shfl_xor(s2, 32);
        float mean = s1 * (1.f / 128.f);
        float var  = s2 * (1.f / 128.f) - mean * mean;
        float rstd = rsqrtf(var + BN_EPS);
        const int c = col0 + wc * 64 + nf * 32 + cl;
        float g = gamma[c] * rstd;
        float b = beta[c] - mean * g;
        #pragma unroll
        for (int mf = 0; mf < 4; ++mf)
            #pragma unroll
            for (int j = 0; j < 16; ++j) {
                int r = row0 + wr * 128 + mf * 32 + (j & 3) + 8 * (j >> 2) + 4 * hl;
                size_t off = (size_t)r * N + c;
                Z[off] = (acc[mf][nf][j] * g + b) * priors[off];
            }
    }
}

// ---------------- sparsemax: one wave per row of 1024, exact Michelot projection ----------------
__device__ __forceinline__ float waveSum(float v) {
    #pragma unroll
    for (int off = 32; off > 0; off >>= 1) v += __shfl_xor(v, off);
    return v;
}

__global__ __launch_bounds__(256)
void sparsemax_kernel(float* __restrict__ Z) {
    const int lane = threadIdx.x & 63;
    const int wid  = threadIdx.x >> 6;
    const size_t row = (size_t)blockIdx.x * 4 + wid;
    float4* zr4 = (float4*)(Z + row * 1024);

    float p[16];
    #pragma unroll
    for (int j = 0; j < 4; ++j) {
        float4 t = zr4[lane * 4 + j];
        p[4 * j + 0] = t.x; p[4 * j + 1] = t.y; p[4 * j + 2] = t.z; p[4 * j + 3] = t.w;
    }

    float s = 0.f;
    #pragma unroll
    for (int i = 0; i < 16; ++i) s += p[i];
    s = waveSum(s);

    float kc  = 1024.f;
    float tau = (s - 1.f) * (1.f / 1024.f);
    for (int it = 0; it < 64; ++it) {
        float s2 = 0.f, c2 = 0.f;
        #pragma unroll
        for (int i = 0; i < 16; ++i) {
            if (p[i] > tau) { s2 += p[i]; c2 += 1.f; }
        }
        s2 = waveSum(s2); c2 = waveSum(c2);
        if (c2 == kc) break;        // support stable -> tau exact
        kc = c2;
        tau = (s2 - 1.f) / c2;
    }

    #pragma unroll
    for (int j = 0; j < 4; ++j) {
        float4 o;
        o.x = fmaxf(p[4 * j + 0] - tau, 0.f);
        o.y = fmaxf(p[4 * j + 1] - tau, 0.f);
        o.z = fmaxf(p[4 * j + 2] - tau, 0.f);
        o.w = fmaxf(p[4 * j + 3] - tau, 0.f);
        zr4[lane * 4 + j] = o;
    }
}

extern "C" void kernel_launch(void* const* d_in, const int* in_sizes, int n_in,
                              void* d_out, int out_size, void* d_ws, size_t ws_size,
                              hipStream_t stream)
{
    const float* priors = (const float*)d_in[0];
    const float* feat   = (const float*)d_in[1];
    const float* W      = (const float*)d_in[2];
    const float* gamma  = (const float*)d_in[3];
    const float* beta   = (const float*)d_in[4];
    float* out = (float*)d_out;

    const int Nf = in_sizes[3];              // 1024
    const int Kf = in_sizes[2] / Nf;         // 2048
    const int Mr = in_sizes[1] / Kf;         // 32768

    _Float16* Ah = (_Float16*)d_ws;                                  // M*K*2 = 128 MB
    _Float16* Wh = (_Float16*)((char*)d_ws + (size_t)Mr * Kf * 2);   // N*K*2 =   4 MB

    {
        int n8 = Mr * (Kf / 8);
        cast_f32_f16<<<(n8 + 255) / 256, 256, 0, stream>>>(feat, Ah, n8);
    }
    {
        int n8 = Nf * (Kf / 8);
        cast_f32_f16<<<(n8 + 255) / 256, 256, 0, stream>>>(W, Wh, n8);
    }

    int nblk = (Mr / 256) * (Nf / 256);      // 512, divisible by 8
    gemm_gbn_kernel<<<nblk, 512, 0, stream>>>(Ah, Wh, priors, gamma, beta, out, Mr, Nf, Kf);

    sparsemax_kernel<<<Mr / 4, 256, 0, stream>>>(out);
}